// Round 10
// baseline (2816.769 us; speedup 1.0000x reference)
//
#include <hip/hip_runtime.h>

#define HID 256
#define HH  64
#define WW  64

typedef _Float16 f16x8 __attribute__((ext_vector_type(8)));
typedef float    f32x4 __attribute__((ext_vector_type(4)));

// LDS-only barrier (no vmcnt drain); sched_barrier fences per skill rule #18.
#define LDS_BARRIER() do {                                   \
    asm volatile("s_waitcnt lgkmcnt(0)" ::: "memory");       \
    __builtin_amdgcn_sched_barrier(0);                       \
    __builtin_amdgcn_s_barrier();                            \
    __builtin_amdgcn_sched_barrier(0);                       \
  } while (0)

// 4 waves (256 thr), 1/SIMD. Serial-path-trimmed step:
//  - pre folded into MFMA C-init (no post-MFMA val add)
//  - lane->4-channel epilogue (no lq-select cndmasks; 4 ILP sigmoid chains)
//  - writes on lanes<16 only; global stores fire-and-forget
__global__ __launch_bounds__(256, 1)
void mrf_scan_kernel(const float* __restrict__ x,
                     const float* __restrict__ w_xh,
                     const float* __restrict__ b_xh,
                     const float* __restrict__ w_hh,
                     const float* __restrict__ b_hh,
                     float* __restrict__ out)
{
    const int n   = blockIdx.x;
    const int tid = threadIdx.x;
    const int l   = tid & 63;
    const int l15 = l & 15;
    const int lq  = l >> 4;
    const int nbase = (tid >> 6) * 64;   // wave's 64-channel slice

    __shared__ __align__(16) _Float16 hbel[WW][HID];   // h of row below, per column
    __shared__ __align__(16) _Float16 hsum[2][HID];    // h_prev + h_below[w_next], ping-pong
    __shared__ __align__(16) float4   xs4[WW];         // per-row x neighbor sums

    // ---- zero-init LDS ----
    {
        unsigned int* z = (unsigned int*)(&hbel[0][0]);
        #pragma unroll
        for (int q = 0; q < (WW*HID/2)/256; ++q) z[tid + 256*q] = 0u;
        ((unsigned int*)(&hsum[0][0]))[tid] = 0u;   // covers both buffers
    }

    // ---- preload w_hh as MFMA B-fragments: B[k][col], col -> nbase+nt*16+l15 ----
    f16x8 Bf[4][8];
    #pragma unroll
    for (int nt = 0; nt < 4; ++nt) {
        const float* wr = w_hh + (size_t)(nbase + nt*16 + l15) * HID;
        #pragma unroll
        for (int kf = 0; kf < 8; ++kf) {
            const int g0 = kf*32 + lq*8;
            f16x8 b;
            #pragma unroll
            for (int j = 0; j < 8; ++j) b[j] = (_Float16)wr[g0 + j];
            Bf[nt][kf] = b;
        }
    }

    // ---- per-lane constants for its 4 channels {nbase + nt*16 + l15} ----
    float wxa[4], wxb[4], wxc[4], bxv[4], bhv[4];
    const int XP = HH*WW;
    float* bptr[4];
    #pragma unroll
    for (int nt = 0; nt < 4; ++nt) {
        const int ch = nbase + nt*16 + l15;
        wxa[nt] = w_xh[ch*3+0];
        wxb[nt] = w_xh[ch*3+1];
        wxc[nt] = w_xh[ch*3+2];
        bxv[nt] = b_xh[ch];
        bhv[nt] = b_hh[ch];
        bptr[nt] = out + ((size_t)n * HID + ch) * (size_t)XP;
    }

    const float* xn = x + (size_t)n * 3 * XP;

    __syncthreads();

    int cur = 0;
    for (int k = 0; k < HH; ++k) {
        const int i    = HH - 1 - k;
        const int flip = ((i & 1) == 0);   // even rows scan right->left

        // ---- stage x neighbor sums for this row (waves 0..2; c = wave) ----
        if (tid < 192) {
            const int c = tid >> 6, w = tid & 63;
            const float* xc = xn + (size_t)c * XP;
            float s = 0.f;
            if (w > 0)    s += xc[i*WW + w - 1];
            if (w < WW-1) s += xc[i*WW + w + 1];
            if (i > 0)    s += xc[(i-1)*WW + w];
            if (i < HH-1) s += xc[(i+1)*WW + w];
            ((float*)&xs4[w])[c] = s;
            if (c == 0) {
                const float cnt = (float)((w>0) + (w<WW-1) + (i>0) + (i<HH-1));
                ((float*)&xs4[w])[3] = cnt;
            }
        }
        LDS_BARRIER();

        const float Fr = ((i != 0) ? 1.f : 0.f) + ((k != 0) ? 1.f : 0.f);
        const int rowoff = i*WW;

        for (int t = 0; t < WW; ++t) {
            const int w  = flip ? (WW-1-t) : t;
            const int wn = (t < WW-1) ? (flip ? (WW-2-t) : (t+1)) : w;

            // ---- LDS reads up front: A-frags, next-col below-h (x4), xsums ----
            f16x8 Af[8];
            #pragma unroll
            for (int kf = 0; kf < 8; ++kf)
                Af[kf] = *(const f16x8*)((const char*)(&hsum[cur][0]) + kf*64 + lq*16);
            _Float16 hb[4];
            #pragma unroll
            for (int nt = 0; nt < 4; ++nt) hb[nt] = hbel[wn][nbase + nt*16 + l15];
            const float4 xv = xs4[w];

            // per-lane x-logit for 4 channels (hidden under MFMA issue)
            const float Ft = Fr + ((t != 0 && t != WW-1) ? 1.f : 0.f) + ((t != 0) ? 1.f : 0.f);
            float pre[4];
            #pragma unroll
            for (int nt = 0; nt < 4; ++nt) {
                float p = xv.w * bxv[nt];
                p = fmaf(xv.x, wxa[nt], p);
                p = fmaf(xv.y, wxb[nt], p);
                p = fmaf(xv.z, wxc[nt], p);
                p = fmaf(Ft,   bhv[nt], p);
                pre[nt] = p;
            }

            // ---- MFMA: per tile 2 accumulators, 4-deep; C-init of cA = pre ----
            float val[4];
            #pragma unroll
            for (int nt = 0; nt < 4; ++nt) {
                f32x4 cA = (f32x4){pre[nt], pre[nt], pre[nt], pre[nt]};
                f32x4 cB = (f32x4){0.f, 0.f, 0.f, 0.f};
                #pragma unroll
                for (int kf = 0; kf < 4; ++kf) {
                    cA = __builtin_amdgcn_mfma_f32_16x16x32_f16(Af[kf],   Bf[nt][kf],   cA, 0, 0, 0);
                    cB = __builtin_amdgcn_mfma_f32_16x16x32_f16(Af[kf+4], Bf[nt][kf+4], cB, 0, 0, 0);
                }
                val[nt] = cA[0] + cB[0];   // all D rows equal (replicated A)
            }

            // ---- 4 independent sigmoid chains (ILP) ----
            float sg[4]; _Float16 h16[4];
            #pragma unroll
            for (int nt = 0; nt < 4; ++nt) {
                const float e = __expf(-val[nt]);
                sg[nt] = __builtin_amdgcn_rcpf(1.f + e);
                h16[nt] = (_Float16)sg[nt];
            }

            // ---- writes on lanes<16 only ----
            if (l < 16) {
                #pragma unroll
                for (int nt = 0; nt < 4; ++nt) {
                    const int ch = nbase + nt*16 + l15;
                    hbel[w][ch] = h16[nt];
                    hsum[cur ^ 1][ch] = (t < WW-1) ? (_Float16)(h16[nt] + hb[nt]) : h16[nt];
                    bptr[nt][rowoff + w] = sg[nt];   // fire-and-forget
                }
            }

            LDS_BARRIER();
            cur ^= 1;
        }
    }
}

extern "C" void kernel_launch(void* const* d_in, const int* in_sizes, int n_in,
                              void* d_out, int out_size, void* d_ws, size_t ws_size,
                              hipStream_t stream) {
    const float* x    = (const float*)d_in[0];
    const float* w_xh = (const float*)d_in[1];
    const float* b_xh = (const float*)d_in[2];
    const float* w_hh = (const float*)d_in[3];
    const float* b_hh = (const float*)d_in[4];
    float* out = (float*)d_out;
    (void)in_sizes; (void)n_in; (void)d_ws; (void)ws_size; (void)out_size;

    mrf_scan_kernel<<<dim3(32), dim3(256), 0, stream>>>(x, w_xh, b_xh, w_hh, b_hh, out);
}